// Round 4
// baseline (483.589 us; speedup 1.0000x reference)
//
#include <hip/hip_runtime.h>
#include <hip/hip_bf16.h>
#include <stdint.h>

// Problem constants
#define NB 2
#define NT 4096
#define NC 768
#define NHEAD 12
#define HS 64
#define MTOK (NB * NT)      // 8192
#define C3 (3 * NC)         // 2304

typedef __bf16 bf16x8 __attribute__((ext_vector_type(8)));
typedef float f32x4 __attribute__((ext_vector_type(4)));

#define KSCALE_LOG2E 0.18033688011f   // (1/sqrt(64)) * log2(e)

__device__ __forceinline__ unsigned short f2bf(float f) {  // RNE
  union { float f; uint32_t u; } v; v.f = f;
  uint32_t r = v.u + 0x7fffu + ((v.u >> 16) & 1u);
  return (unsigned short)(r >> 16);
}
__device__ __forceinline__ unsigned short bft(float f) {   // truncate
  return (unsigned short)(__builtin_bit_cast(unsigned int, f) >> 16);
}

// async global->LDS, 16B per lane: lane i lands at ldsbase + i*16B.
__device__ __forceinline__ void gload_lds16(const unsigned short* g, unsigned short* ldsbase) {
  __builtin_amdgcn_global_load_lds(
      (const __attribute__((address_space(1))) unsigned int*)g,
      (__attribute__((address_space(3))) unsigned int*)ldsbase, 16, 0, 0);
}

__device__ __forceinline__ f32x4 mfma16(bf16x8 a, bf16x8 b, f32x4 c) {
  return __builtin_amdgcn_mfma_f32_16x16x32_bf16(a, b, c, 0, 0, 0);
}

// ---------------- fused prep: cast x, transpose-cast w_attn & w_proj ----------------
__global__ __launch_bounds__(256) void prep(
    const float* __restrict__ x, const float* __restrict__ wa, const float* __restrict__ wp,
    unsigned short* __restrict__ xb, unsigned short* __restrict__ waT,
    unsigned short* __restrict__ wpT) {
  const int N4 = MTOK * NC / 4;   // x, float4 groups
  const int NA = C3 * NC;         // w_attn^T elements
  int gid = blockIdx.x * 256 + threadIdx.x;
  if (gid < N4) {
    float4 v = reinterpret_cast<const float4*>(x)[gid];
    ushort4 o;
    o.x = f2bf(v.x); o.y = f2bf(v.y); o.z = f2bf(v.z); o.w = f2bf(v.w);
    reinterpret_cast<ushort4*>(xb)[gid] = o;
  } else if (gid < N4 + NA) {
    int idx = gid - N4;                 // waT[n][k], n<C3, k<NC
    int n = idx / NC, k = idx - n * NC;
    waT[idx] = f2bf(wa[(size_t)k * C3 + n]);
  } else if (gid < N4 + NA + NC * NC) {
    int idx = gid - N4 - NA;            // wpT[n][k]
    int n = idx / NC, k = idx - n * NC;
    wpT[idx] = f2bf(wp[(size_t)k * NC + n]);
  }
}

// V slice of qkv [B][T][3C] -> vT [B*NH][HS][T]  (bf16)
__global__ __launch_bounds__(256) void transpose_v(
    const unsigned short* __restrict__ qkv, unsigned short* __restrict__ vT) {
  __shared__ unsigned short tile[64][72];
  const int t0 = blockIdx.x * 64;
  const int bh = blockIdx.y;
  const int b = bh / NHEAD, h = bh - b * NHEAD;
  const unsigned short* src = qkv + (size_t)b * NT * C3 + 2 * NC + h * HS;
  const int r = threadIdx.x >> 3;
  const int c8 = (threadIdx.x & 7) * 8;
  uint4 v0 = *reinterpret_cast<const uint4*>(src + (size_t)(t0 + r) * C3 + c8);
  uint4 v1 = *reinterpret_cast<const uint4*>(src + (size_t)(t0 + r + 32) * C3 + c8);
  *reinterpret_cast<uint4*>(&tile[r][c8]) = v0;
  *reinterpret_cast<uint4*>(&tile[r + 32][c8]) = v1;
  __syncthreads();
  unsigned short* dst = vT + (size_t)bh * HS * NT + t0;
#pragma unroll
  for (int half = 0; half < 2; ++half) {
    const int d = r + half * 32;
    ushort4 o0, o1;
    o0.x = tile[c8 + 0][d]; o0.y = tile[c8 + 1][d];
    o0.z = tile[c8 + 2][d]; o0.w = tile[c8 + 3][d];
    o1.x = tile[c8 + 4][d]; o1.y = tile[c8 + 5][d];
    o1.z = tile[c8 + 6][d]; o1.w = tile[c8 + 7][d];
    *reinterpret_cast<ushort4*>(dst + (size_t)d * NT + c8) = o0;
    *reinterpret_cast<ushort4*>(dst + (size_t)d * NT + c8 + 4) = o1;
  }
}

// ---------------- GEMM 128x128: C[M,N] = A[M,K] @ Bt[N,K]^T ----------------
// global_load_lds width=16 staging, XOR-swizzled storage -> conflict-free ds_read_b128.
// QSCALE: multiply output columns < NC by KSCALE_LOG2E (folds softmax scale into Q).
template <int OUT_BF16, int QSCALE>
__global__ __launch_bounds__(256) void gemm128(
    const unsigned short* __restrict__ A,   // [M][K]
    const unsigned short* __restrict__ Bt,  // [N][K]
    void* __restrict__ Cout, int M, int N, int K) {
  __shared__ unsigned short As[128 * 64];
  __shared__ unsigned short Bs[128 * 64];

  const int tid = threadIdx.x;
  const int wave = tid >> 6;
  const int lane = tid & 63;
  const int li = lane & 15;
  const int lq = lane >> 4;
  const int wm = wave & 1;
  const int wn = wave >> 1;
  const int row0 = blockIdx.y * 128;
  const int col0 = blockIdx.x * 128;

  const int crow = lane >> 3;
  const int cchunk = ((lane & 7) ^ crow) * 8;

  f32x4 acc[4][4] = {};

  for (int k0 = 0; k0 < K; k0 += 64) {
#pragma unroll
    for (int i = 0; i < 4; ++i) {
      const int R = wave * 32 + i * 8;
      gload_lds16(A + (size_t)(row0 + R + crow) * K + k0 + cchunk, &As[R * 64]);
      gload_lds16(Bt + (size_t)(col0 + R + crow) * K + k0 + cchunk, &Bs[R * 64]);
    }
    __syncthreads();

#pragma unroll
    for (int ks = 0; ks < 2; ++ks) {
      bf16x8 af[4], bf[4];
#pragma unroll
      for (int f = 0; f < 4; ++f) {
        const int arow = wm * 64 + f * 16 + li;
        af[f] = *reinterpret_cast<const bf16x8*>(&As[arow * 64 + (((ks * 4 + lq) ^ (li & 7)) << 3)]);
        const int brow = wn * 64 + f * 16 + li;
        bf[f] = *reinterpret_cast<const bf16x8*>(&Bs[brow * 64 + (((ks * 4 + lq) ^ (li & 7)) << 3)]);
      }
#pragma unroll
      for (int fa = 0; fa < 4; ++fa)
#pragma unroll
        for (int fb = 0; fb < 4; ++fb)
          acc[fa][fb] = mfma16(af[fa], bf[fb], acc[fa][fb]);
    }
    __syncthreads();
  }

  if (OUT_BF16) {
    unsigned short* Cb = (unsigned short*)Cout;
#pragma unroll
    for (int fa = 0; fa < 4; ++fa) {
      const int gr = row0 + wm * 64 + fa * 16 + lq * 4;
#pragma unroll
      for (int fb = 0; fb < 4; ++fb) {
        const int gc = col0 + wn * 64 + fb * 16 + li;
        const float sc = (QSCALE && gc < NC) ? KSCALE_LOG2E : 1.0f;
#pragma unroll
        for (int r = 0; r < 4; ++r)
          Cb[(size_t)(gr + r) * N + gc] = f2bf(acc[fa][fb][r] * sc);
      }
    }
  } else {
    float* Cf = (float*)Cout;
#pragma unroll
    for (int fa = 0; fa < 4; ++fa) {
      const int gr = row0 + wm * 64 + fa * 16 + lq * 4;
#pragma unroll
      for (int fb = 0; fb < 4; ++fb) {
        const int gc = col0 + wn * 64 + fb * 16 + li;
#pragma unroll
        for (int r = 0; r < 4; ++r)
          Cf[(size_t)(gr + r) * N + gc] = acc[fa][fb][r];
      }
    }
  }
}

// ---------------- Flash attention (causal, pipelined) ----------------
// Grid: (T/128, NH, B). Block 256 = 4 waves. Wave w owns rows {w*16..} (strip0,
// lower 64) and {64+w*16..} (strip1, upper 64). S computed one tile ahead;
// K/V double-buffered in LDS; one barrier per tile. Q pre-scaled by
// KSCALE_LOG2E in gemm1 -> scores are already in log2 domain.
__device__ __forceinline__ void qk_tile(const unsigned short* __restrict__ Ksrc,
                                        const bf16x8 aq[2][2], f32x4 (*sacc)[4],
                                        int li, int lq, bool do0) {
  const f32x4 z = {};
#pragma unroll
  for (int n = 0; n < 4; ++n) { sacc[0][n] = z; sacc[1][n] = z; }
#pragma unroll
  for (int ks = 0; ks < 2; ++ks) {
#pragma unroll
    for (int n = 0; n < 4; ++n) {
      const bf16x8 bk = *reinterpret_cast<const bf16x8*>(
          Ksrc + (n * 16 + li) * 64 + (((ks * 4 + lq) ^ (li & 7)) << 3));
      if (do0) sacc[0][n] = mfma16(aq[0][ks], bk, sacc[0][n]);
      sacc[1][n] = mfma16(aq[1][ks], bk, sacc[1][n]);
    }
  }
}

template <bool MASK>
__device__ __forceinline__ void exp_store(const f32x4* s4, float* ls,
                                          unsigned short* __restrict__ Ps,
                                          int stripRowBase, int lq, int li,
                                          int colbase, int qrowbase) {
#pragma unroll
  for (int n = 0; n < 4; ++n) {
    const int colt = colbase + n * 16 + li;
    const int c8p = n * 2 + (li >> 3);
#pragma unroll
    for (int r = 0; r < 4; ++r) {
      float v = s4[n][r];
      if (MASK && colt > qrowbase + r) v = -INFINITY;
      const float p = __builtin_amdgcn_exp2f(v);
      ls[r] += p;
      const int prow = stripRowBase + lq * 4 + r;
      Ps[prow * 64 + ((c8p ^ (prow & 7)) << 3) + (li & 7)] = bft(p);
    }
  }
}

__global__ __launch_bounds__(256, 3) void attn(
    const unsigned short* __restrict__ qkv,   // [B][T][3C]
    const unsigned short* __restrict__ vT,    // [B*NH][HS][T]
    unsigned short* __restrict__ out) {       // [B][T][C]
  constexpr int BQ = 128, BKV = 64;
  __shared__ unsigned short Ks[2][64 * 64];
  __shared__ unsigned short Vts[2][64 * 64];
  __shared__ unsigned short Ps[128 * 64];

  const int tid = threadIdx.x;
  const int wave = tid >> 6;
  const int lane = tid & 63;
  const int li = lane & 15;
  const int lq = lane >> 4;
  const int q0 = ((int)gridDim.x - 1 - (int)blockIdx.x) * BQ;  // heavy first
  const int h = blockIdx.y;
  const int b = blockIdx.z;
  const int bh = b * NHEAD + h;

  const size_t baseQ = (size_t)b * NT * C3 + (size_t)h * HS;
  const size_t baseK = baseQ + NC;
  const unsigned short* vbase = vT + (size_t)bh * HS * NT;

  const int sb0 = wave * 16;        // strip0 row base (within block)
  const int sb1 = 64 + wave * 16;   // strip1 row base

  // Q fragments (A-layout), pre-scaled in gemm1
  bf16x8 aq[2][2];
#pragma unroll
  for (int s = 0; s < 2; ++s) {
    const int qrow = q0 + (s ? sb1 : sb0) + li;
#pragma unroll
    for (int ks = 0; ks < 2; ++ks)
      aq[s][ks] = *reinterpret_cast<const bf16x8*>(qkv + baseQ + (size_t)qrow * C3 + ks * 32 + lq * 8);
  }

  f32x4 o[2][4] = {};
  f32x4 sacc[2][4];
  float lsum[2][4] = {{0.f, 0.f, 0.f, 0.f}, {0.f, 0.f, 0.f, 0.f}};

  const int sr = tid >> 3;
  const int sc8 = tid & 7;
  const int slotK0 = sr * 8 + (sc8 ^ (sr & 7));
  const int slotK1 = (sr + 32) * 8 + (sc8 ^ (sr & 7));

  const int tmax = q0 + 64;   // last tile start; >= 64 always

  // ---- prologue: tile 0 -> LDS buf0; prefetch tile 1 into regs ----
  uint4 kr0 = *reinterpret_cast<const uint4*>(qkv + baseK + (size_t)sr * C3 + sc8 * 8);
  uint4 kr1 = *reinterpret_cast<const uint4*>(qkv + baseK + (size_t)(sr + 32) * C3 + sc8 * 8);
  uint4 vr0 = *reinterpret_cast<const uint4*>(vbase + (size_t)sr * NT + sc8 * 8);
  uint4 vr1 = *reinterpret_cast<const uint4*>(vbase + (size_t)(sr + 32) * NT + sc8 * 8);
  reinterpret_cast<uint4*>(Ks[0])[slotK0] = kr0;
  reinterpret_cast<uint4*>(Ks[0])[slotK1] = kr1;
  reinterpret_cast<uint4*>(Vts[0])[slotK0] = vr0;
  reinterpret_cast<uint4*>(Vts[0])[slotK1] = vr1;
  kr0 = *reinterpret_cast<const uint4*>(qkv + baseK + (size_t)(64 + sr) * C3 + sc8 * 8);
  kr1 = *reinterpret_cast<const uint4*>(qkv + baseK + (size_t)(64 + sr + 32) * C3 + sc8 * 8);
  vr0 = *reinterpret_cast<const uint4*>(vbase + (size_t)sr * NT + 64 + sc8 * 8);
  vr1 = *reinterpret_cast<const uint4*>(vbase + (size_t)(sr + 32) * NT + 64 + sc8 * 8);
  __syncthreads();
  qk_tile(Ks[0], aq, sacc, li, lq, true);

  for (int t0 = 0; t0 <= tmax; t0 += BKV) {
    const int buf = (t0 >> 6) & 1, nbuf = buf ^ 1;
    const int tn = t0 + BKV;

    // stage next tile (regs -> LDS nbuf), then prefetch tile after next
    if (tn <= tmax) {
      reinterpret_cast<uint4*>(Ks[nbuf])[slotK0] = kr0;
      reinterpret_cast<uint4*>(Ks[nbuf])[slotK1] = kr1;
      reinterpret_cast<uint4*>(Vts[nbuf])[slotK0] = vr0;
      reinterpret_cast<uint4*>(Vts[nbuf])[slotK1] = vr1;
      const int tp = t0 + 2 * BKV;
      if (tp <= tmax) {
        kr0 = *reinterpret_cast<const uint4*>(qkv + baseK + (size_t)(tp + sr) * C3 + sc8 * 8);
        kr1 = *reinterpret_cast<const uint4*>(qkv + baseK + (size_t)(tp + sr + 32) * C3 + sc8 * 8);
        vr0 = *reinterpret_cast<const uint4*>(vbase + (size_t)sr * NT + tp + sc8 * 8);
        vr1 = *reinterpret_cast<const uint4*>(vbase + (size_t)(sr + 32) * NT + tp + sc8 * 8);
      }
    }

    // ---- exp phase (block-uniform case split) ----
    if (t0 < q0) {                   // fully unmasked, both strips
      exp_store<false>(sacc[0], lsum[0], Ps, sb0, lq, li, t0, 0);
      exp_store<false>(sacc[1], lsum[1], Ps, sb1, lq, li, t0, 0);
    } else if (t0 == q0) {           // diag for strip0; strip1 unmasked
      exp_store<true>(sacc[0], lsum[0], Ps, sb0, lq, li, t0, q0 + sb0 + lq * 4);
      exp_store<false>(sacc[1], lsum[1], Ps, sb1, lq, li, t0, 0);
    } else {                         // t0 == q0+64: strip0 dead; diag for strip1
      exp_store<true>(sacc[1], lsum[1], Ps, sb1, lq, li, t0, q0 + sb1 + lq * 4);
    }

    // Ps rows are wave-private: LDS-op completion suffices
    asm volatile("s_waitcnt lgkmcnt(0)" ::: "memory");

    // ---- O += P V ----
    if (t0 < tmax) {
#pragma unroll
      for (int ks = 0; ks < 2; ++ks) {
        const int swz = ((ks * 4 + lq) ^ (li & 7)) << 3;
        const bf16x8 ap0 = *reinterpret_cast<const bf16x8*>(Ps + (sb0 + li) * 64 + swz);
        const bf16x8 ap1 = *reinterpret_cast<const bf16x8*>(Ps + (sb1 + li) * 64 + swz);
#pragma unroll
        for (int n = 0; n < 4; ++n) {
          const bf16x8 bv = *reinterpret_cast<const bf16x8*>(Vts[buf] + (n * 16 + li) * 64 + swz);
          o[0][n] = mfma16(ap0, bv, o[0][n]);
          o[1][n] = mfma16(ap1, bv, o[1][n]);
        }
      }
    } else {                         // last tile: strip1 only
#pragma unroll
      for (int ks = 0; ks < 2; ++ks) {
        const int swz = ((ks * 4 + lq) ^ (li & 7)) << 3;
        const bf16x8 ap1 = *reinterpret_cast<const bf16x8*>(Ps + (sb1 + li) * 64 + swz);
#pragma unroll
        for (int n = 0; n < 4; ++n) {
          const bf16x8 bv = *reinterpret_cast<const bf16x8*>(Vts[buf] + (n * 16 + li) * 64 + swz);
          o[1][n] = mfma16(ap1, bv, o[1][n]);
        }
      }
    }

    __syncthreads();   // all waves done writing nbuf & reading buf

    // ---- S for next tile (from nbuf) ----
    if (tn <= tmax) qk_tile(Ks[nbuf], aq, sacc, li, lq, /*do0=*/tn != tmax);
  }

  // ---- deferred l reduction + epilogue ----
  const size_t obase = (size_t)b * NT * NC + (size_t)h * HS;
#pragma unroll
  for (int s = 0; s < 2; ++s) {
    const int sb = s ? sb1 : sb0;
#pragma unroll
    for (int r = 0; r < 4; ++r) {
      float v = lsum[s][r];
      v += __shfl_xor(v, 1, 64);
      v += __shfl_xor(v, 2, 64);
      v += __shfl_xor(v, 4, 64);
      v += __shfl_xor(v, 8, 64);
      const float inv = 1.0f / v;
      const int row = q0 + sb + lq * 4 + r;
#pragma unroll
      for (int n = 0; n < 4; ++n)
        out[obase + (size_t)row * NC + n * 16 + li] = bft(o[s][n][r] * inv);
    }
  }
}

// ---------------- launch ----------------
extern "C" void kernel_launch(void* const* d_in, const int* in_sizes, int n_in,
                              void* d_out, int out_size, void* d_ws, size_t ws_size,
                              hipStream_t stream) {
  const float* x = (const float*)d_in[0];       // [B,T,C]
  const float* w_attn = (const float*)d_in[1];  // [C, 3C]
  const float* w_proj = (const float*)d_in[2];  // [C, C]
  float* outp = (float*)d_out;

  unsigned short* xb   = (unsigned short*)d_ws;                 // [MTOK][C]
  unsigned short* waT  = xb  + (size_t)MTOK * NC;               // [3C][C]
  unsigned short* wpT  = waT + (size_t)C3 * NC;                 // [C][C]
  unsigned short* qkvb = wpT + (size_t)NC * NC;                 // [MTOK][3C]
  unsigned short* aob  = qkvb + (size_t)MTOK * C3;              // [MTOK][C]
  unsigned short* vTb  = aob + (size_t)MTOK * NC;               // [B*NH][HS][T]

  {
    const int total = MTOK * NC / 4 + C3 * NC + NC * NC;
    prep<<<(total + 255) / 256, 256, 0, stream>>>(x, w_attn, w_proj, xb, waT, wpT);
  }

  // qkv = x @ w_attn (Q columns pre-scaled) -> bf16 [MTOK][3C]
  gemm128<1, 1><<<dim3(C3 / 128, MTOK / 128), 256, 0, stream>>>(xb, waT, qkvb, MTOK, C3, NC);

  // V -> vT [B*NH][HS][T]
  transpose_v<<<dim3(NT / 64, NB * NHEAD), 256, 0, stream>>>(qkvb, vTb);

  // attention -> bf16 [MTOK][C]
  attn<<<dim3(NT / 128, NHEAD, NB), 256, 0, stream>>>(qkvb, vTb, aob);

  // out = att_out @ w_proj -> fp32 d_out
  gemm128<0, 0><<<dim3(NC / 128, MTOK / 128), 256, 0, stream>>>(aob, wpT, outp, MTOK, NC, NC);
}

// Round 5
// 404.022 us; speedup vs baseline: 1.1969x; 1.1969x over previous
//
#include <hip/hip_runtime.h>
#include <hip/hip_bf16.h>
#include <stdint.h>

// Problem constants
#define NB 2
#define NT 4096
#define NC 768
#define NHEAD 12
#define HS 64
#define MTOK (NB * NT)      // 8192
#define C3 (3 * NC)         // 2304

typedef __bf16 bf16x8 __attribute__((ext_vector_type(8)));
typedef float f32x4 __attribute__((ext_vector_type(4)));

#define KSCALE_LOG2E 0.18033688011f   // (1/sqrt(64)) * log2(e)

__device__ __forceinline__ unsigned short f2bf(float f) {  // RNE
  union { float f; uint32_t u; } v; v.f = f;
  uint32_t r = v.u + 0x7fffu + ((v.u >> 16) & 1u);
  return (unsigned short)(r >> 16);
}
__device__ __forceinline__ unsigned short bft(float f) {   // truncate
  return (unsigned short)(__builtin_bit_cast(unsigned int, f) >> 16);
}

// async global->LDS, 16B per lane: lane i lands at ldsbase + i*16B.
__device__ __forceinline__ void gload_lds16(const unsigned short* g, unsigned short* ldsbase) {
  __builtin_amdgcn_global_load_lds(
      (const __attribute__((address_space(1))) unsigned int*)g,
      (__attribute__((address_space(3))) unsigned int*)ldsbase, 16, 0, 0);
}

__device__ __forceinline__ f32x4 mfma16(bf16x8 a, bf16x8 b, f32x4 c) {
  return __builtin_amdgcn_mfma_f32_16x16x32_bf16(a, b, c, 0, 0, 0);
}

// ---------------- fused prep: cast x, transpose-cast w_attn & w_proj ----------------
__global__ __launch_bounds__(256) void prep(
    const float* __restrict__ x, const float* __restrict__ wa, const float* __restrict__ wp,
    unsigned short* __restrict__ xb, unsigned short* __restrict__ waT,
    unsigned short* __restrict__ wpT) {
  const int N4 = MTOK * NC / 4;   // x, float4 groups
  const int NA = C3 * NC;         // w_attn^T elements
  int gid = blockIdx.x * 256 + threadIdx.x;
  if (gid < N4) {
    float4 v = reinterpret_cast<const float4*>(x)[gid];
    ushort4 o;
    o.x = f2bf(v.x); o.y = f2bf(v.y); o.z = f2bf(v.z); o.w = f2bf(v.w);
    reinterpret_cast<ushort4*>(xb)[gid] = o;
  } else if (gid < N4 + NA) {
    int idx = gid - N4;                 // waT[n][k], n<C3, k<NC
    int n = idx / NC, k = idx - n * NC;
    waT[idx] = f2bf(wa[(size_t)k * C3 + n]);
  } else if (gid < N4 + NA + NC * NC) {
    int idx = gid - N4 - NA;            // wpT[n][k]
    int n = idx / NC, k = idx - n * NC;
    wpT[idx] = f2bf(wp[(size_t)k * NC + n]);
  }
}

// V slice of qkv [B][T][3C] -> vT [B*NH][HS][T]  (bf16)
__global__ __launch_bounds__(256) void transpose_v(
    const unsigned short* __restrict__ qkv, unsigned short* __restrict__ vT) {
  __shared__ unsigned short tile[64][72];
  const int t0 = blockIdx.x * 64;
  const int bh = blockIdx.y;
  const int b = bh / NHEAD, h = bh - b * NHEAD;
  const unsigned short* src = qkv + (size_t)b * NT * C3 + 2 * NC + h * HS;
  const int r = threadIdx.x >> 3;
  const int c8 = (threadIdx.x & 7) * 8;
  uint4 v0 = *reinterpret_cast<const uint4*>(src + (size_t)(t0 + r) * C3 + c8);
  uint4 v1 = *reinterpret_cast<const uint4*>(src + (size_t)(t0 + r + 32) * C3 + c8);
  *reinterpret_cast<uint4*>(&tile[r][c8]) = v0;
  *reinterpret_cast<uint4*>(&tile[r + 32][c8]) = v1;
  __syncthreads();
  unsigned short* dst = vT + (size_t)bh * HS * NT + t0;
#pragma unroll
  for (int half = 0; half < 2; ++half) {
    const int d = r + half * 32;
    ushort4 o0, o1;
    o0.x = tile[c8 + 0][d]; o0.y = tile[c8 + 1][d];
    o0.z = tile[c8 + 2][d]; o0.w = tile[c8 + 3][d];
    o1.x = tile[c8 + 4][d]; o1.y = tile[c8 + 5][d];
    o1.z = tile[c8 + 6][d]; o1.w = tile[c8 + 7][d];
    *reinterpret_cast<ushort4*>(dst + (size_t)d * NT + c8) = o0;
    *reinterpret_cast<ushort4*>(dst + (size_t)d * NT + c8 + 4) = o1;
  }
}

// ---------------- GEMM 128x128: C[M,N] = A[M,K] @ Bt[N,K]^T ----------------
template <int OUT_BF16, int QSCALE>
__global__ __launch_bounds__(256) void gemm128(
    const unsigned short* __restrict__ A,   // [M][K]
    const unsigned short* __restrict__ Bt,  // [N][K]
    void* __restrict__ Cout, int M, int N, int K) {
  __shared__ unsigned short As[128 * 64];
  __shared__ unsigned short Bs[128 * 64];

  const int tid = threadIdx.x;
  const int wave = tid >> 6;
  const int lane = tid & 63;
  const int li = lane & 15;
  const int lq = lane >> 4;
  const int wm = wave & 1;
  const int wn = wave >> 1;
  const int row0 = blockIdx.y * 128;
  const int col0 = blockIdx.x * 128;

  const int crow = lane >> 3;
  const int cchunk = ((lane & 7) ^ crow) * 8;

  f32x4 acc[4][4] = {};

  for (int k0 = 0; k0 < K; k0 += 64) {
#pragma unroll
    for (int i = 0; i < 4; ++i) {
      const int R = wave * 32 + i * 8;
      gload_lds16(A + (size_t)(row0 + R + crow) * K + k0 + cchunk, &As[R * 64]);
      gload_lds16(Bt + (size_t)(col0 + R + crow) * K + k0 + cchunk, &Bs[R * 64]);
    }
    __syncthreads();

#pragma unroll
    for (int ks = 0; ks < 2; ++ks) {
      bf16x8 af[4], bf[4];
#pragma unroll
      for (int f = 0; f < 4; ++f) {
        const int arow = wm * 64 + f * 16 + li;
        af[f] = *reinterpret_cast<const bf16x8*>(&As[arow * 64 + (((ks * 4 + lq) ^ (li & 7)) << 3)]);
        const int brow = wn * 64 + f * 16 + li;
        bf[f] = *reinterpret_cast<const bf16x8*>(&Bs[brow * 64 + (((ks * 4 + lq) ^ (li & 7)) << 3)]);
      }
#pragma unroll
      for (int fa = 0; fa < 4; ++fa)
#pragma unroll
        for (int fb = 0; fb < 4; ++fb)
          acc[fa][fb] = mfma16(af[fa], bf[fb], acc[fa][fb]);
    }
    __syncthreads();
  }

  if (OUT_BF16) {
    unsigned short* Cb = (unsigned short*)Cout;
#pragma unroll
    for (int fa = 0; fa < 4; ++fa) {
      const int gr = row0 + wm * 64 + fa * 16 + lq * 4;
#pragma unroll
      for (int fb = 0; fb < 4; ++fb) {
        const int gc = col0 + wn * 64 + fb * 16 + li;
        const float sc = (QSCALE && gc < NC) ? KSCALE_LOG2E : 1.0f;
#pragma unroll
        for (int r = 0; r < 4; ++r)
          Cb[(size_t)(gr + r) * N + gc] = f2bf(acc[fa][fb][r] * sc);
      }
    }
  } else {
    float* Cf = (float*)Cout;
#pragma unroll
    for (int fa = 0; fa < 4; ++fa) {
      const int gr = row0 + wm * 64 + fa * 16 + lq * 4;
#pragma unroll
      for (int fb = 0; fb < 4; ++fb) {
        const int gc = col0 + wn * 64 + fb * 16 + li;
#pragma unroll
        for (int r = 0; r < 4; ++r)
          Cf[(size_t)(gr + r) * N + gc] = acc[fa][fb][r];
      }
    }
  }
}

// ---------------- Flash attention (causal, 1 barrier/tile, fully inlined) ----------------
// Grid: (T/128, NH, B). Block 256 = 4 waves. Wave w owns strip0 rows w*16.. and
// strip1 rows 64+w*16. Q pre-scaled by KSCALE_LOG2E (scores already log2-domain).
// Per tile: ds_write staged regs -> [B]; issue loads t+2 (full-iteration latency
// cover before the barrier drain); QK from [A]; exp -> Ps (wave-private, lgkm only);
// PV from [A]; barrier.

#define EXP_STORE(S, LS, SBASE, DOMASK, QROWB)                                 \
  do {                                                                         \
    _Pragma("unroll") for (int n = 0; n < 4; ++n) {                            \
      const int colt = t0 + n * 16 + li;                                       \
      const int c8p = n * 2 + (li >> 3);                                       \
      _Pragma("unroll") for (int r = 0; r < 4; ++r) {                          \
        float v = S[n][r];                                                     \
        if (DOMASK && colt > (QROWB) + r) v = -INFINITY;                       \
        const float p = __builtin_amdgcn_exp2f(v);                             \
        LS[r] += p;                                                            \
        const int prow = (SBASE) + lq * 4 + r;                                 \
        Ps[prow * 64 + ((c8p ^ (prow & 7)) << 3) + (li & 7)] = bft(p);         \
      }                                                                        \
    }                                                                          \
  } while (0)

__global__ __launch_bounds__(256) void attn(
    const unsigned short* __restrict__ qkv,   // [B][T][3C]
    const unsigned short* __restrict__ vT,    // [B*NH][HS][T]
    unsigned short* __restrict__ out) {       // [B][T][C]
  __shared__ unsigned short Ks[2][64 * 64];
  __shared__ unsigned short Vts[2][64 * 64];
  __shared__ unsigned short Ps[128 * 64];

  const int tid = threadIdx.x;
  const int wave = tid >> 6;
  const int lane = tid & 63;
  const int li = lane & 15;
  const int lq = lane >> 4;
  const int q0 = ((int)gridDim.x - 1 - (int)blockIdx.x) * 128;  // heavy first
  const int h = blockIdx.y;
  const int b = blockIdx.z;
  const int bh = b * NHEAD + h;

  const size_t baseQ = (size_t)b * NT * C3 + (size_t)h * HS;
  const size_t baseK = baseQ + NC;
  const unsigned short* vbase = vT + (size_t)bh * HS * NT;

  const int sb0 = wave * 16;
  const int sb1 = 64 + wave * 16;

  // Q fragments (A-layout), pre-scaled in gemm1
  bf16x8 aq0[2], aq1[2];
#pragma unroll
  for (int ks = 0; ks < 2; ++ks) {
    aq0[ks] = *reinterpret_cast<const bf16x8*>(qkv + baseQ + (size_t)(q0 + sb0 + li) * C3 + ks * 32 + lq * 8);
    aq1[ks] = *reinterpret_cast<const bf16x8*>(qkv + baseQ + (size_t)(q0 + sb1 + li) * C3 + ks * 32 + lq * 8);
  }

  f32x4 o0[4] = {}, o1[4] = {};
  float l0[4] = {0.f, 0.f, 0.f, 0.f}, l1[4] = {0.f, 0.f, 0.f, 0.f};

  const int sr = tid >> 3;           // staging row 0..31
  const int sc8 = tid & 7;           // staging 16B-chunk
  const int slotK0 = sr * 8 + (sc8 ^ (sr & 7));
  const int slotK1 = (sr + 32) * 8 + (sc8 ^ (sr & 7));

  const int tmax = q0 + 64;          // last tile start

  // ---- prologue: tile 0 -> LDS[0]; tile 1 -> regs ----
  uint4 kr0 = *reinterpret_cast<const uint4*>(qkv + baseK + (size_t)sr * C3 + sc8 * 8);
  uint4 kr1 = *reinterpret_cast<const uint4*>(qkv + baseK + (size_t)(sr + 32) * C3 + sc8 * 8);
  uint4 vr0 = *reinterpret_cast<const uint4*>(vbase + (size_t)sr * NT + sc8 * 8);
  uint4 vr1 = *reinterpret_cast<const uint4*>(vbase + (size_t)(sr + 32) * NT + sc8 * 8);
  reinterpret_cast<uint4*>(Ks[0])[slotK0] = kr0;
  reinterpret_cast<uint4*>(Ks[0])[slotK1] = kr1;
  reinterpret_cast<uint4*>(Vts[0])[slotK0] = vr0;
  reinterpret_cast<uint4*>(Vts[0])[slotK1] = vr1;
  kr0 = *reinterpret_cast<const uint4*>(qkv + baseK + (size_t)(64 + sr) * C3 + sc8 * 8);
  kr1 = *reinterpret_cast<const uint4*>(qkv + baseK + (size_t)(64 + sr + 32) * C3 + sc8 * 8);
  vr0 = *reinterpret_cast<const uint4*>(vbase + (size_t)sr * NT + 64 + sc8 * 8);
  vr1 = *reinterpret_cast<const uint4*>(vbase + (size_t)(sr + 32) * NT + 64 + sc8 * 8);
  __syncthreads();

  for (int t0 = 0; t0 <= tmax; t0 += 64) {
    const int abuf = (t0 >> 6) & 1;
    const int tn = t0 + 64;

    // ---- stage K/V(t+1) regs -> [B]; issue loads for t+2 ----
    if (tn <= tmax) {
      const int nb = abuf ^ 1;
      reinterpret_cast<uint4*>(Ks[nb])[slotK0] = kr0;
      reinterpret_cast<uint4*>(Ks[nb])[slotK1] = kr1;
      reinterpret_cast<uint4*>(Vts[nb])[slotK0] = vr0;
      reinterpret_cast<uint4*>(Vts[nb])[slotK1] = vr1;
      const int tp = tn + 64;
      if (tp <= tmax) {
        kr0 = *reinterpret_cast<const uint4*>(qkv + baseK + (size_t)(tp + sr) * C3 + sc8 * 8);
        kr1 = *reinterpret_cast<const uint4*>(qkv + baseK + (size_t)(tp + sr + 32) * C3 + sc8 * 8);
        vr0 = *reinterpret_cast<const uint4*>(vbase + (size_t)sr * NT + tp + sc8 * 8);
        vr1 = *reinterpret_cast<const uint4*>(vbase + (size_t)(sr + 32) * NT + tp + sc8 * 8);
      }
    }

    // ---- S = Q K^T from Ks[abuf] ----
    const bool do0 = (t0 != tmax);   // strip0 dead on last tile
    f32x4 s0[4], s1[4];
    {
      const f32x4 z = {};
#pragma unroll
      for (int n = 0; n < 4; ++n) { s0[n] = z; s1[n] = z; }
#pragma unroll
      for (int ks = 0; ks < 2; ++ks) {
#pragma unroll
        for (int n = 0; n < 4; ++n) {
          const bf16x8 bk = *reinterpret_cast<const bf16x8*>(
              Ks[abuf] + (n * 16 + li) * 64 + (((ks * 4 + lq) ^ (li & 7)) << 3));
          if (do0) s0[n] = mfma16(aq0[ks], bk, s0[n]);
          s1[n] = mfma16(aq1[ks], bk, s1[n]);
        }
      }
    }

    // ---- exp phase (block-uniform case split) ----
    if (t0 < q0) {
      EXP_STORE(s0, l0, sb0, false, 0);
      EXP_STORE(s1, l1, sb1, false, 0);
    } else if (t0 == q0) {
      EXP_STORE(s0, l0, sb0, true, q0 + sb0 + lq * 4);
      EXP_STORE(s1, l1, sb1, false, 0);
    } else {
      EXP_STORE(s1, l1, sb1, true, q0 + sb1 + lq * 4);
    }

    // Ps rows are wave-private: LDS-op completion suffices (no barrier)
    asm volatile("s_waitcnt lgkmcnt(0)" ::: "memory");

    // ---- O += P V from Vts[abuf] ----
#pragma unroll
    for (int ks = 0; ks < 2; ++ks) {
      const int swz = ((ks * 4 + lq) ^ (li & 7)) << 3;
      const bf16x8 ap0 = *reinterpret_cast<const bf16x8*>(Ps + (sb0 + li) * 64 + swz);
      const bf16x8 ap1 = *reinterpret_cast<const bf16x8*>(Ps + (sb1 + li) * 64 + swz);
#pragma unroll
      for (int n = 0; n < 4; ++n) {
        const bf16x8 bv = *reinterpret_cast<const bf16x8*>(Vts[abuf] + (n * 16 + li) * 64 + swz);
        if (do0) o0[n] = mfma16(ap0, bv, o0[n]);
        o1[n] = mfma16(ap1, bv, o1[n]);
      }
    }

    __syncthreads();  // drains vmcnt (t+2 loads had full iteration in flight)
  }

  // ---- deferred l reduction + epilogue ----
  const size_t obase = (size_t)b * NT * NC + (size_t)h * HS;
#pragma unroll
  for (int r = 0; r < 4; ++r) {
    float v = l0[r];
    v += __shfl_xor(v, 1, 64);
    v += __shfl_xor(v, 2, 64);
    v += __shfl_xor(v, 4, 64);
    v += __shfl_xor(v, 8, 64);
    const float inv = 1.0f / v;
    const int row = q0 + sb0 + lq * 4 + r;
#pragma unroll
    for (int n = 0; n < 4; ++n)
      out[obase + (size_t)row * NC + n * 16 + li] = bft(o0[n][r] * inv);
  }
#pragma unroll
  for (int r = 0; r < 4; ++r) {
    float v = l1[r];
    v += __shfl_xor(v, 1, 64);
    v += __shfl_xor(v, 2, 64);
    v += __shfl_xor(v, 4, 64);
    v += __shfl_xor(v, 8, 64);
    const float inv = 1.0f / v;
    const int row = q0 + sb1 + lq * 4 + r;
#pragma unroll
    for (int n = 0; n < 4; ++n)
      out[obase + (size_t)row * NC + n * 16 + li] = bft(o1[n][r] * inv);
  }
}

// ---------------- launch ----------------
extern "C" void kernel_launch(void* const* d_in, const int* in_sizes, int n_in,
                              void* d_out, int out_size, void* d_ws, size_t ws_size,
                              hipStream_t stream) {
  const float* x = (const float*)d_in[0];       // [B,T,C]
  const float* w_attn = (const float*)d_in[1];  // [C, 3C]
  const float* w_proj = (const float*)d_in[2];  // [C, C]
  float* outp = (float*)d_out;

  unsigned short* xb   = (unsigned short*)d_ws;                 // [MTOK][C]
  unsigned short* waT  = xb  + (size_t)MTOK * NC;               // [3C][C]
  unsigned short* wpT  = waT + (size_t)C3 * NC;                 // [C][C]
  unsigned short* qkvb = wpT + (size_t)NC * NC;                 // [MTOK][3C]
  unsigned short* aob  = qkvb + (size_t)MTOK * C3;              // [MTOK][C]
  unsigned short* vTb  = aob + (size_t)MTOK * NC;               // [B*NH][HS][T]

  {
    const int total = MTOK * NC / 4 + C3 * NC + NC * NC;
    prep<<<(total + 255) / 256, 256, 0, stream>>>(x, w_attn, w_proj, xb, waT, wpT);
  }

  // qkv = x @ w_attn (Q columns pre-scaled) -> bf16 [MTOK][3C]
  gemm128<1, 1><<<dim3(C3 / 128, MTOK / 128), 256, 0, stream>>>(xb, waT, qkvb, MTOK, C3, NC);

  // V -> vT [B*NH][HS][T]
  transpose_v<<<dim3(NT / 64, NB * NHEAD), 256, 0, stream>>>(qkvb, vTb);

  // attention -> bf16 [MTOK][C]
  attn<<<dim3(NT / 128, NHEAD, NB), 256, 0, stream>>>(qkvb, vTb, aob);

  // out = att_out @ w_proj -> fp32 d_out
  gemm128<0, 0><<<dim3(NC / 128, MTOK / 128), 256, 0, stream>>>(aob, wpT, outp, MTOK, NC, NC);
}